// Round 8
// baseline (1458.364 us; speedup 1.0000x reference)
//
#include <hip/hip_runtime.h>
#include <stdint.h>

// Problem constants
constexpr int CIN  = 32;
constexpr int COLS_PER_B = 8192;               // COUT*ATOM
constexpr long long NTOT = 1048576;            // B * COLS_PER_B columns
constexpr float NTOTF = 1048576.0f;

typedef float f32x2 __attribute__((ext_vector_type(2)));

// Stats kernel tiling: TK=128 cols/tile, LINEAR 32x128 LDS rows (512B) with
// XOR-swizzle (both-sides: pre-swizzled global source + swizzled read).
constexpr int TK    = 128;
constexpr int GRID1 = 1024;  // 4 blocks/CU
constexpr int TPB   = 8;     // 8192 tiles / 1024 blocks

// ws layout (floats): [0..1023] G accum, [1024..1055] s accum,
//                     [1056..2079] W (invsqrt*gamma), [2080..2111] bias

__global__ __launch_bounds__(256, 4) void stats_kernel(const float* __restrict__ x,
                                                       float* __restrict__ acc) {
    __shared__ float tile[2][CIN * TK];   // 2 x 16 KB double buffer
    __shared__ float ssum[CIN];
    const int t  = threadIdx.x;
    const int w  = t >> 6;        // wave 0..3 = k-quarter & staging quarter
    const int l  = t & 63;
    const int ti = l >> 3;        // 0..7 -> A rows {ti+8d}
    const int tj = l & 7;         // 0..7 -> B rows {tj+8e}

    float accg[4][4] = {};
    float asum[4] = {};
    if (t < CIN) ssum[t] = 0.f;

    const int tile0 = blockIdx.x * TPB;

    // Stage one tile: wave w stages rows 8w..8w+7, 2 rows (1024B) per call.
    // LDS dest is wave-uniform base + lane*16 (linear); the SWIZZLE lives in
    // the per-lane GLOBAL address: chunk (l&31)^(row&7), so LDS row r holds
    // logical chunk c at physical slot c^(r&7)  (T2 both-sides-or-neither).
    auto stage = [&](int buf, int tileid) {
        const int b    = tileid >> 6;            // 64 tiles per batch
        const int col0 = (tileid & 63) << 7;     // *128
        const float* base = x + (size_t)b * CIN * COLS_PER_B + col0;
        #pragma unroll
        for (int cc = 0; cc < 4; ++cc) {
            const int row   = w * 8 + cc * 2 + (l >> 5);
            const int chunk = (l & 31) ^ (row & 7);
            const float* gp = base + (size_t)row * COLS_PER_B + chunk * 4;
            __builtin_amdgcn_global_load_lds(
                (const __attribute__((address_space(1))) uint32_t*)gp,
                (__attribute__((address_space(3))) uint32_t*)&tile[buf][(w * 8 + cc * 2) * TK],
                16, 0, 0);
        }
    };

    stage(0, tile0);
    __syncthreads();            // tile0 resident (also covers ssum init)

    int buf = 0;
    for (int tt = 0; tt < TPB; ++tt) {
        if (tt + 1 < TPB) stage(buf ^ 1, tile0 + tt + 1);   // in flight during compute
        // wave w covers k-chunks k4 = 8w..8w+7 (32 cols of 128)
        #pragma unroll
        for (int s = 0; s < 8; ++s) {
            const int k4 = w * 8 + s;
            float4 av[4], bv[4];
            #pragma unroll
            for (int d = 0; d < 4; ++d)
                av[d] = *(const float4*)&tile[buf][(ti + 8 * d) * TK + ((k4 ^ ti) << 2)];
            #pragma unroll
            for (int e = 0; e < 4; ++e)
                bv[e] = *(const float4*)&tile[buf][(tj + 8 * e) * TK + ((k4 ^ tj) << 2)];
            #pragma unroll
            for (int d = 0; d < 4; ++d) {
                asum[d] += av[d].x + av[d].y + av[d].z + av[d].w;
                #pragma unroll
                for (int e = 0; e < 4; ++e) {
                    accg[d][e] += av[d].x * bv[e].x + av[d].y * bv[e].y
                                + av[d].z * bv[e].z + av[d].w * bv[e].w;
                }
            }
        }
        __syncthreads();   // readers done with buf; next-tile loads drained
        buf ^= 1;
    }

    // cross-wave reduction via LDS (reuse tile[0] as flat 4x1024 scratch)
    float* flat = &tile[0][0];
    #pragma unroll
    for (int d = 0; d < 4; ++d)
        #pragma unroll
        for (int e = 0; e < 4; ++e)
            flat[w * 1024 + (ti + 8 * d) * 32 + (tj + 8 * e)] = accg[d][e];
    if (tj == 0) {
        #pragma unroll
        for (int d = 0; d < 4; ++d) atomicAdd(&ssum[ti + 8 * d], asum[d]);
    }
    __syncthreads();
    #pragma unroll
    for (int q = 0; q < 4; ++q) {
        const int idx = t + q * 256;
        const float v = flat[idx] + flat[1024 + idx] + flat[2048 + idx] + flat[3072 + idx];
        atomicAdd(&acc[idx], v);
    }
    if (t < CIN) atomicAdd(&acc[1024 + t], ssum[t]);
}

__global__ __launch_bounds__(1024) void newton_kernel(const float* __restrict__ acc,
                                                      const float* __restrict__ gamma,
                                                      const float* __restrict__ beta,
                                                      float* __restrict__ outp) {
    __shared__ float sn[32 * 33], p[32 * 33], t1[32 * 33], t2[32 * 33];
    __shared__ float mean[32], diag[32], trs[1];
    const int t = threadIdx.x;
    const int i = t >> 5, j = t & 31;

    if (t < 32) mean[t] = acc[1024 + t] * (1.0f / NTOTF);
    __syncthreads();
    const float sig = (acc[t] - NTOTF * mean[i] * mean[j]) * (1.0f / (NTOTF - 1.0f));
    if (i == j) diag[i] = sig;
    __syncthreads();
    if (t == 0) {
        float tr = 0.f;
        for (int k = 0; k < 32; ++k) tr += diag[k];
        trs[0] = tr;
    }
    __syncthreads();
    const float tr = trs[0];
    sn[i * 33 + j] = sig / tr;
    p[i * 33 + j]  = (i == j) ? 1.0f : 0.0f;
    __syncthreads();

    for (int it = 0; it < 5; ++it) {
        // P^3*Sn = (P*P) @ (P*Sn): both sub-products in one phase
        float a = 0.f, c = 0.f;
        #pragma unroll
        for (int k = 0; k < 32; ++k) {
            const float pik = p[i * 33 + k];
            a += pik * p[k * 33 + j];
            c += pik * sn[k * 33 + j];
        }
        t1[i * 33 + j] = a;
        t2[i * 33 + j] = c;
        __syncthreads();
        float v = 0.f;
        #pragma unroll
        for (int k = 0; k < 32; ++k) v += t1[i * 33 + k] * t2[k * 33 + j];
        const float pn = 1.5f * p[i * 33 + j] - 0.5f * v;
        __syncthreads();
        p[i * 33 + j] = pn;
        __syncthreads();
    }

    const float r = rsqrtf(tr);
    const float wv = p[i * 33 + j] * r * gamma[j];   // fold gamma into W
    t1[i * 33 + j] = wv;
    outp[t] = wv;                                    // W: 1024 floats
    __syncthreads();
    if (t < 32) {
        float bb = beta[t];
        for (int k = 0; k < 32; ++k) bb -= mean[k] * t1[k * 33 + t];
        outp[1024 + t] = bb;                         // bias: 32 floats
    }
}

// W via constant address space -> uniform s_load into SGPRs; inner loop is
// v_fmac_f32 vacc, s_w, v_x.
typedef const __attribute__((address_space(4))) float cfloat;

__global__ __launch_bounds__(256, 4) void apply_kernel(const float* __restrict__ x,
                                                       const float* __restrict__ wmp,
                                                       float* __restrict__ out) {
    cfloat* wm = (cfloat*)wmp;
    const size_t tid  = (size_t)blockIdx.x * 256 + threadIdx.x;
    const size_t col2 = tid * 2;          // 2 columns per thread
    const size_t b    = col2 >> 13;       // /8192
    const size_t c    = col2 & 8191;
    const float* xp = x + b * (size_t)(CIN * COLS_PER_B) + c;
    float* op       = out + b * (size_t)(CIN * COLS_PER_B) + c;

    float2 accv[32];
    #pragma unroll
    for (int j = 0; j < 32; ++j) {
        const float bv = wm[1024 + j];
        accv[j] = make_float2(bv, bv);
    }
    #pragma unroll
    for (int i = 0; i < 32; ++i) {
        const float2 v = *(const float2*)(xp + (size_t)i * COLS_PER_B);
        #pragma unroll
        for (int j = 0; j < 32; ++j) {
            const float sv = wm[i * 32 + j];  // SGPR operand
            accv[j].x += v.x * sv;
            accv[j].y += v.y * sv;
        }
    }
    // Nontemporal: out is write-once; don't evict L3-resident x.
    #pragma unroll
    for (int j = 0; j < 32; ++j) {
        f32x2 v = { accv[j].x, accv[j].y };
        __builtin_nontemporal_store(v, (f32x2*)(op + (size_t)j * COLS_PER_B));
    }
}

extern "C" void kernel_launch(void* const* d_in, const int* in_sizes, int n_in,
                              void* d_out, int out_size, void* d_ws, size_t ws_size,
                              hipStream_t stream) {
    const float* x     = (const float*)d_in[0];
    const float* gamma = (const float*)d_in[1];
    const float* beta  = (const float*)d_in[2];
    float* out = (float*)d_out;
    float* acc = (float*)d_ws;            // 1056 accum + 1056 result floats

    (void)hipMemsetAsync(acc, 0, 1056 * sizeof(float), stream);
    stats_kernel<<<GRID1, 256, 0, stream>>>(x, acc);
    newton_kernel<<<1, 1024, 0, stream>>>(acc, gamma, beta, acc + 1056);
    apply_kernel<<<(NTOT / 2) / 256, 256, 0, stream>>>(x, acc + 1056, out);
}

// Round 9
// 463.858 us; speedup vs baseline: 3.1440x; 3.1440x over previous
//
#include <hip/hip_runtime.h>
#include <stdint.h>

// Problem constants
constexpr int CIN  = 32;
constexpr int COLS_PER_B = 8192;               // COUT*ATOM
constexpr long long NTOT = 1048576;            // B * COLS_PER_B columns
constexpr float NTOTF = 1048576.0f;

typedef float f32x2 __attribute__((ext_vector_type(2)));

// Stats kernel tiling: TK=128 cols/tile, LINEAR 32x128 LDS rows (512B) with
// XOR-swizzle (both-sides: pre-swizzled global source + swizzled read).
constexpr int TK    = 128;
constexpr int GRID1 = 1024;  // 4 blocks/CU
constexpr int TPB   = 8;     // 8192 tiles / 1024 blocks

// ws layout (floats): [0..1023] G accum, [1024..1055] s accum,
//                     [1056..2079] W (invsqrt*gamma), [2080..2111] bias

// NOTE: min-waves arg = 2 (NOT 4). (256,4) capped VGPR at 64 < live set
// (~90) -> accumulator spilled to scratch: 2.4 GB WRITE_SIZE, 10x slowdown
// (measured R8). Cap 256 lets the allocator fit the 4x4 tile + staging.
__global__ __launch_bounds__(256, 2) void stats_kernel(const float* __restrict__ x,
                                                       float* __restrict__ acc) {
    __shared__ float tile[2][CIN * TK];   // 2 x 16 KB double buffer
    __shared__ float ssum[CIN];
    const int t  = threadIdx.x;
    const int w  = t >> 6;        // wave 0..3 = k-quarter & staging quarter
    const int l  = t & 63;
    const int ti = l >> 3;        // 0..7 -> A rows {ti+8d}
    const int tj = l & 7;         // 0..7 -> B rows {tj+8e}

    float accg[4][4] = {};
    float asum[4] = {};
    if (t < CIN) ssum[t] = 0.f;

    const int tile0 = blockIdx.x * TPB;

    // Stage one tile: wave w stages rows 8w..8w+7, 2 rows (1024B) per call.
    // LDS dest is wave-uniform base + lane*16 (linear); the SWIZZLE lives in
    // the per-lane GLOBAL address: chunk (l&31)^(row&7), so LDS row r holds
    // logical chunk c at physical slot c^(r&7)  (T2 both-sides-or-neither).
    auto stage = [&](int buf, int tileid) {
        const int b    = tileid >> 6;            // 64 tiles per batch
        const int col0 = (tileid & 63) << 7;     // *128
        const float* base = x + (size_t)b * CIN * COLS_PER_B + col0;
        #pragma unroll
        for (int cc = 0; cc < 4; ++cc) {
            const int row   = w * 8 + cc * 2 + (l >> 5);
            const int chunk = (l & 31) ^ (row & 7);
            const float* gp = base + (size_t)row * COLS_PER_B + chunk * 4;
            __builtin_amdgcn_global_load_lds(
                (const __attribute__((address_space(1))) uint32_t*)gp,
                (__attribute__((address_space(3))) uint32_t*)&tile[buf][(w * 8 + cc * 2) * TK],
                16, 0, 0);
        }
    };

    stage(0, tile0);
    __syncthreads();            // tile0 resident (also covers ssum init)

    int buf = 0;
    for (int tt = 0; tt < TPB; ++tt) {
        if (tt + 1 < TPB) stage(buf ^ 1, tile0 + tt + 1);   // in flight during compute
        // wave w covers k-chunks k4 = 8w..8w+7 (32 cols of 128)
        #pragma unroll
        for (int s = 0; s < 8; ++s) {
            const int k4 = w * 8 + s;
            float4 av[4], bv[4];
            #pragma unroll
            for (int d = 0; d < 4; ++d)
                av[d] = *(const float4*)&tile[buf][(ti + 8 * d) * TK + ((k4 ^ ti) << 2)];
            #pragma unroll
            for (int e = 0; e < 4; ++e)
                bv[e] = *(const float4*)&tile[buf][(tj + 8 * e) * TK + ((k4 ^ tj) << 2)];
            #pragma unroll
            for (int d = 0; d < 4; ++d) {
                asum[d] += av[d].x + av[d].y + av[d].z + av[d].w;
                #pragma unroll
                for (int e = 0; e < 4; ++e) {
                    accg[d][e] += av[d].x * bv[e].x + av[d].y * bv[e].y
                                + av[d].z * bv[e].z + av[d].w * bv[e].w;
                }
            }
        }
        __syncthreads();   // readers done with buf; next-tile loads drained
        buf ^= 1;
    }

    // cross-wave reduction via LDS (reuse tile[0] as flat 4x1024 scratch)
    float* flat = &tile[0][0];
    #pragma unroll
    for (int d = 0; d < 4; ++d)
        #pragma unroll
        for (int e = 0; e < 4; ++e)
            flat[w * 1024 + (ti + 8 * d) * 32 + (tj + 8 * e)] = accg[d][e];
    if (tj == 0) {
        #pragma unroll
        for (int d = 0; d < 4; ++d) atomicAdd(&ssum[ti + 8 * d], asum[d]);
    }
    __syncthreads();
    #pragma unroll
    for (int q = 0; q < 4; ++q) {
        const int idx = t + q * 256;
        const float v = flat[idx] + flat[1024 + idx] + flat[2048 + idx] + flat[3072 + idx];
        atomicAdd(&acc[idx], v);
    }
    if (t < CIN) atomicAdd(&acc[1024 + t], ssum[t]);
}

__global__ __launch_bounds__(1024) void newton_kernel(const float* __restrict__ acc,
                                                      const float* __restrict__ gamma,
                                                      const float* __restrict__ beta,
                                                      float* __restrict__ outp) {
    __shared__ float sn[32 * 33], p[32 * 33], t1[32 * 33], t2[32 * 33];
    __shared__ float mean[32], diag[32], trs[1];
    const int t = threadIdx.x;
    const int i = t >> 5, j = t & 31;

    if (t < 32) mean[t] = acc[1024 + t] * (1.0f / NTOTF);
    __syncthreads();
    const float sig = (acc[t] - NTOTF * mean[i] * mean[j]) * (1.0f / (NTOTF - 1.0f));
    if (i == j) diag[i] = sig;
    __syncthreads();
    if (t == 0) {
        float tr = 0.f;
        for (int k = 0; k < 32; ++k) tr += diag[k];
        trs[0] = tr;
    }
    __syncthreads();
    const float tr = trs[0];
    sn[i * 33 + j] = sig / tr;
    p[i * 33 + j]  = (i == j) ? 1.0f : 0.0f;
    __syncthreads();

    for (int it = 0; it < 5; ++it) {
        // P^3*Sn = (P*P) @ (P*Sn): both sub-products in one phase
        float a = 0.f, c = 0.f;
        #pragma unroll
        for (int k = 0; k < 32; ++k) {
            const float pik = p[i * 33 + k];
            a += pik * p[k * 33 + j];
            c += pik * sn[k * 33 + j];
        }
        t1[i * 33 + j] = a;
        t2[i * 33 + j] = c;
        __syncthreads();
        float v = 0.f;
        #pragma unroll
        for (int k = 0; k < 32; ++k) v += t1[i * 33 + k] * t2[k * 33 + j];
        const float pn = 1.5f * p[i * 33 + j] - 0.5f * v;
        __syncthreads();
        p[i * 33 + j] = pn;
        __syncthreads();
    }

    const float r = rsqrtf(tr);
    const float wv = p[i * 33 + j] * r * gamma[j];   // fold gamma into W
    t1[i * 33 + j] = wv;
    outp[t] = wv;                                    // W: 1024 floats
    __syncthreads();
    if (t < 32) {
        float bb = beta[t];
        for (int k = 0; k < 32; ++k) bb -= mean[k] * t1[k * 33 + t];
        outp[1024 + t] = bb;                         // bias: 32 floats
    }
}

// W via constant address space -> uniform s_load broadcasts.
typedef const __attribute__((address_space(4))) float cfloat;

// Same fix: (256,4) forced VGPR=64 < accv[32] alone (64 regs) -> spill churn
// (R6: WRITE 139MB vs 128 ideal, VALU issue 6x pure-FMA). Cap 256.
__global__ __launch_bounds__(256, 2) void apply_kernel(const float* __restrict__ x,
                                                       const float* __restrict__ wmp,
                                                       float* __restrict__ out) {
    cfloat* wm = (cfloat*)wmp;
    const size_t tid  = (size_t)blockIdx.x * 256 + threadIdx.x;
    const size_t col2 = tid * 2;          // 2 columns per thread
    const size_t b    = col2 >> 13;       // /8192
    const size_t c    = col2 & 8191;
    const float* xp = x + b * (size_t)(CIN * COLS_PER_B) + c;
    float* op       = out + b * (size_t)(CIN * COLS_PER_B) + c;

    float2 accv[32];
    #pragma unroll
    for (int j = 0; j < 32; ++j) {
        const float bv = wm[1024 + j];
        accv[j] = make_float2(bv, bv);
    }
    #pragma unroll
    for (int i = 0; i < 32; ++i) {
        const float2 v = *(const float2*)(xp + (size_t)i * COLS_PER_B);
        #pragma unroll
        for (int j = 0; j < 32; ++j) {
            const float sv = wm[i * 32 + j];  // SGPR operand
            accv[j].x += v.x * sv;
            accv[j].y += v.y * sv;
        }
    }
    // Nontemporal: out is write-once; don't evict L3-resident x.
    #pragma unroll
    for (int j = 0; j < 32; ++j) {
        f32x2 v = { accv[j].x, accv[j].y };
        __builtin_nontemporal_store(v, (f32x2*)(op + (size_t)j * COLS_PER_B));
    }
}

extern "C" void kernel_launch(void* const* d_in, const int* in_sizes, int n_in,
                              void* d_out, int out_size, void* d_ws, size_t ws_size,
                              hipStream_t stream) {
    const float* x     = (const float*)d_in[0];
    const float* gamma = (const float*)d_in[1];
    const float* beta  = (const float*)d_in[2];
    float* out = (float*)d_out;
    float* acc = (float*)d_ws;            // 1056 accum + 1056 result floats

    (void)hipMemsetAsync(acc, 0, 1056 * sizeof(float), stream);
    stats_kernel<<<GRID1, 256, 0, stream>>>(x, acc);
    newton_kernel<<<1, 1024, 0, stream>>>(acc, gamma, beta, acc + 1056);
    apply_kernel<<<(NTOT / 2) / 256, 256, 0, stream>>>(x, acc + 1056, out);
}